// Round 1
// baseline (1235.833 us; speedup 1.0000x reference)
//
#include <hip/hip_runtime.h>
#include <math.h>

#define N      128
#define LOGN   7
#define NSQ    (N * N)          // 16384
#define VOL    (N * N * N)      // 2097152
#define NSHELL 64
#define BTOT   8
#define FPI    3.14159265358979323846f

// ---------------------------------------------------------------------------
// 128-point radix-2 Stockham FFT in LDS. 64 threads, each does one butterfly
// per stage. bufA/bufB ping-pong; returns pointer holding the result
// (natural order, forward transform, sign = -1).
// ---------------------------------------------------------------------------
__device__ inline float2* stockham128(float2* bufA, float2* bufB, int t) {
    float2* src = bufA;
    float2* dst = bufB;
#pragma unroll
    for (int s = 0; s < LOGN; ++s) {
        const int Ns = 1 << s;
        __syncthreads();
        float2 v0 = src[t];
        float2 v1 = src[t + 64];
        const int m = t & (Ns - 1);
        float ang = -FPI * (float)m / (float)Ns;
        float sw, cw;
        __sincosf(ang, &sw, &cw);
        float wx = v1.x * cw - v1.y * sw;
        float wy = v1.x * sw + v1.y * cw;
        const int d = ((t >> s) << (s + 1)) + m;
        dst[d]      = make_float2(v0.x + wx, v0.y + wy);
        dst[d + Ns] = make_float2(v0.x - wx, v0.y - wy);
        float2* tmp = src; src = dst; dst = tmp;
    }
    __syncthreads();
    return src;   // after 7 swaps the last-written buffer is src
}

// ---------------------------------------------------------------------------
// Pass 1: pack Z = ref + i*pred, FFT along z (contiguous axis).
// One 64-thread block per line (b, x, y).
// ---------------------------------------------------------------------------
__global__ __launch_bounds__(64) void k_fftz_pack(const float* __restrict__ ref,
                                                  const float* __restrict__ pred,
                                                  float2* __restrict__ Z, int b0) {
    __shared__ float2 bufA[N], bufB[N];
    const int t = threadIdx.x;
    const unsigned line = blockIdx.x;
    const int y  = line & (N - 1);
    const int x  = (line >> LOGN) & (N - 1);
    const int bl = line >> (2 * LOGN);
    const size_t inbase = (size_t)(b0 + bl) * VOL + (size_t)x * NSQ + (size_t)y * N;
    const size_t zbase  = (size_t)bl * VOL + (size_t)x * NSQ + (size_t)y * N;
    bufA[t]      = make_float2(ref[inbase + t],      pred[inbase + t]);
    bufA[t + 64] = make_float2(ref[inbase + t + 64], pred[inbase + t + 64]);
    float2* res = stockham128(bufA, bufB, t);
    Z[zbase + t]      = res[t];
    Z[zbase + t + 64] = res[t + 64];
}

// ---------------------------------------------------------------------------
// Pass 2: FFT along y (stride N). One block per line (b, x, z).
// ---------------------------------------------------------------------------
__global__ __launch_bounds__(64) void k_ffty(float2* __restrict__ Z) {
    __shared__ float2 bufA[N], bufB[N];
    const int t = threadIdx.x;
    const unsigned line = blockIdx.x;
    const int z  = line & (N - 1);
    const int x  = (line >> LOGN) & (N - 1);
    const int bl = line >> (2 * LOGN);
    const size_t base = (size_t)bl * VOL + (size_t)x * NSQ + (size_t)z;
    bufA[t]      = Z[base + (size_t)t * N];
    bufA[t + 64] = Z[base + (size_t)(t + 64) * N];
    float2* res = stockham128(bufA, bufB, t);
    Z[base + (size_t)t * N]        = res[t];
    Z[base + (size_t)(t + 64) * N] = res[t + 64];
}

// ---------------------------------------------------------------------------
// Pass 3: FFT along x (stride N*N). One block per line (b, y, z).
// ---------------------------------------------------------------------------
__global__ __launch_bounds__(64) void k_fftx(float2* __restrict__ Z) {
    __shared__ float2 bufA[N], bufB[N];
    const int t = threadIdx.x;
    const unsigned line = blockIdx.x;
    const int z  = line & (N - 1);
    const int y  = (line >> LOGN) & (N - 1);
    const int bl = line >> (2 * LOGN);
    const size_t base = (size_t)bl * VOL + (size_t)y * N + (size_t)z;
    bufA[t]      = Z[base + (size_t)t * NSQ];
    bufA[t + 64] = Z[base + (size_t)(t + 64) * NSQ];
    float2* res = stockham128(bufA, bufB, t);
    Z[base + (size_t)t * NSQ]        = res[t];
    Z[base + (size_t)(t + 64) * NSQ] = res[t + 64];
}

// ---------------------------------------------------------------------------
// Pass 4: shell reduction. Recover F1/F2 from Z(k), Z(-k); accumulate
// cross / |F1|^2 / |F2|^2 into per-block LDS bins, then global atomics.
// 256 blocks per batch, each handles 8192 consecutive k.
// ---------------------------------------------------------------------------
__global__ __launch_bounds__(256) void k_reduce(const float2* __restrict__ Z,
                                                const int* __restrict__ sidx,
                                                float* __restrict__ accum, int b0) {
    __shared__ float sh[NSHELL * 3];
    const int tid = threadIdx.x;
    for (int i = tid; i < NSHELL * 3; i += 256) sh[i] = 0.f;
    __syncthreads();
    const int bl    = blockIdx.x >> 8;     // 256 chunks per batch
    const int chunk = blockIdx.x & 255;
    const size_t zb = (size_t)bl * VOL;
    const int k0 = chunk * 8192;
    for (int i = 0; i < 8192; i += 256) {
        const int k = k0 + i + tid;
        const int s = sidx[k];
        if (s < NSHELL) {
            const int x = k >> (2 * LOGN);
            const int y = (k >> LOGN) & (N - 1);
            const int z = k & (N - 1);
            const int mk = (((N - x) & (N - 1)) << (2 * LOGN)) |
                           (((N - y) & (N - 1)) << LOGN) |
                           ((N - z) & (N - 1));
            const float2 A  = Z[zb + k];
            const float2 Bv = Z[zb + mk];
            // F1 = (A + conj(Bv)) / 2 ; F2 = (A - conj(Bv)) / (2i)
            const float F1x = 0.5f * (A.x + Bv.x);
            const float F1y = 0.5f * (A.y - Bv.y);
            const float F2x = 0.5f * (A.y + Bv.y);
            const float F2y = 0.5f * (Bv.x - A.x);
            const float cross = F1x * F2x + F1y * F2y;
            const float p1 = F1x * F1x + F1y * F1y;
            const float p2 = F2x * F2x + F2y * F2y;
            atomicAdd(&sh[s * 3 + 0], cross);
            atomicAdd(&sh[s * 3 + 1], p1);
            atomicAdd(&sh[s * 3 + 2], p2);
        }
    }
    __syncthreads();
    float* acc = accum + (size_t)(b0 + bl) * (NSHELL * 3);
    for (int i = tid; i < NSHELL * 3; i += 256) atomicAdd(&acc[i], sh[i]);
}

// ---------------------------------------------------------------------------
// Pass 5: FSC + loss. 512 threads = 8 batches x 64 shells.
// ---------------------------------------------------------------------------
__global__ __launch_bounds__(512) void k_final(const float* __restrict__ accum,
                                               float* __restrict__ out) {
    __shared__ float red[8];
    const int tid = threadIdx.x;                 // tid = b*64 + s
    const float* a = accum + (size_t)tid * 3;
    const float num = a[0], d1 = a[1], d2 = a[2];
    const float fsc = num / (sqrtf(d1 * d2) + 1e-8f);
    float v = fsc * fsc;
#pragma unroll
    for (int off = 32; off > 0; off >>= 1) v += __shfl_down(v, off);
    if ((tid & 63) == 0) red[tid >> 6] = v;
    __syncthreads();
    if (tid == 0) {
        float ssum = 0.f;
#pragma unroll
        for (int i = 0; i < 8; ++i) ssum += red[i];
        out[0] = 1.0f - ssum / 512.0f;
    }
}

extern "C" void kernel_launch(void* const* d_in, const int* in_sizes, int n_in,
                              void* d_out, int out_size, void* d_ws, size_t ws_size,
                              hipStream_t stream) {
    const float* ref  = (const float*)d_in[0];
    const float* pred = (const float*)d_in[1];
    const int*   sidx = (const int*)d_in[2];
    float* out = (float*)d_out;

    char*   ws    = (char*)d_ws;
    float*  accum = (float*)ws;                    // 8*64*3 floats = 6144 B
    float2* Zbuf  = (float2*)(ws + 8192);          // per-batch 16 MiB complex

    const size_t zbytes = (size_t)VOL * sizeof(float2);
    int cap = 1;
    if (ws_size > 8192) {
        size_t c = (ws_size - 8192) / zbytes;
        cap = (c < 1) ? 1 : (c > BTOT ? BTOT : (int)c);
    }

    hipMemsetAsync(accum, 0, BTOT * NSHELL * 3 * sizeof(float), stream);

    for (int b0 = 0; b0 < BTOT; b0 += cap) {
        const int nb = (BTOT - b0 < cap) ? (BTOT - b0) : cap;
        const int nlines = nb * NSQ;
        k_fftz_pack<<<nlines, 64, 0, stream>>>(ref, pred, Zbuf, b0);
        k_ffty<<<nlines, 64, 0, stream>>>(Zbuf);
        k_fftx<<<nlines, 64, 0, stream>>>(Zbuf);
        k_reduce<<<nb * 256, 256, 0, stream>>>(Zbuf, sidx, accum, b0);
    }
    k_final<<<1, 512, 0, stream>>>(accum, out);
}

// Round 2
// 479.681 us; speedup vs baseline: 2.5764x; 2.5764x over previous
//
#include <hip/hip_runtime.h>
#include <math.h>

#define N      128
#define LOGN   7
#define NSQ    (N * N)          // 16384
#define VOL    (N * N * N)      // 2097152
#define NSHELL 64
#define BTOT   8
#define FPI    3.14159265358979323846f

#define TL     16               // lines (z-columns) per tile
#define TP     (TL + 1)         // padded row stride in float2 (17)

// ---------------------------------------------------------------------------
// 16 simultaneous 128-point radix-2 Stockham FFTs over an LDS tile.
// Tile layout: buf[coord * TP + line], coord = FFT axis index (0..127),
// line = which of the 16 independent lines. 256 threads: lane bf = t&63 is
// the butterfly index (same twiddle for all its lines -> one sincos per
// stage), grp = (t>>6)*4 selects 4 lines. Pad TP=17 keeps every wave access
// at the uniform-bank 4-cycle b64 floor.
// ---------------------------------------------------------------------------
__device__ inline float2* fft16(float2* A, float2* B, int t) {
    const int bf  = t & 63;
    const int grp = (t >> 6) << 2;
    float2* src = A;
    float2* dst = B;
#pragma unroll
    for (int s = 0; s < LOGN; ++s) {
        const int Ns = 1 << s;
        const int m  = bf & (Ns - 1);
        const int d  = ((bf >> s) << (s + 1)) + m;
        float sw, cw;
        __sincosf(-FPI * (float)m / (float)Ns, &sw, &cw);
        __syncthreads();
#pragma unroll
        for (int l = 0; l < 4; ++l) {
            const int line = grp + l;
            const float2 v0 = src[bf * TP + line];
            const float2 v1 = src[(bf + 64) * TP + line];
            const float wx = v1.x * cw - v1.y * sw;
            const float wy = v1.x * sw + v1.y * cw;
            dst[d * TP + line]        = make_float2(v0.x + wx, v0.y + wy);
            dst[(d + Ns) * TP + line] = make_float2(v0.x - wx, v0.y - wy);
        }
        float2* tmp = src; src = dst; dst = tmp;
    }
    __syncthreads();
    return src;   // 7 swaps -> result in B
}

// ---------------------------------------------------------------------------
// Pass 1: pack Z = ref + i*pred and FFT along z (contiguous axis).
// Block = (b, x, y-tile of 16): a contiguous 16 KiB chunk of the volume.
// Tile line = y, coord = z.
// ---------------------------------------------------------------------------
__global__ __launch_bounds__(256) void k_fftz_pack(const float* __restrict__ ref,
                                                   const float* __restrict__ pred,
                                                   float2* __restrict__ Z, int b0) {
    __shared__ float2 A[N * TP], B[N * TP];
    const int t  = threadIdx.x;
    const int yt = blockIdx.x & 7;
    const int x  = (blockIdx.x >> 3) & (N - 1);
    const int bl = blockIdx.x >> 10;
    const size_t inbase = (size_t)(b0 + bl) * VOL + (size_t)x * NSQ + (size_t)yt * TL * N;
    const size_t zbase  = (size_t)bl * VOL + (size_t)x * NSQ + (size_t)yt * TL * N;
#pragma unroll
    for (int i = 0; i < 8; ++i) {
        const int elem = i * 256 + t;           // 0..2047, contiguous in memory
        const int z = elem & (N - 1);
        const int j = elem >> LOGN;             // line (y within tile)
        A[z * TP + j] = make_float2(ref[inbase + elem], pred[inbase + elem]);
    }
    float2* res = fft16(A, B, t);
#pragma unroll
    for (int i = 0; i < 8; ++i) {
        const int elem = i * 256 + t;
        const int z = elem & (N - 1);
        const int j = elem >> LOGN;
        Z[zbase + elem] = res[z * TP + j];
    }
}

// ---------------------------------------------------------------------------
// Passes 2 & 3: FFT along a strided axis. Block = (b, mid, z-tile of 16).
// Element address: base + j*stride + zz, j = FFT coord, zz = line.
//   y-pass: stride = N,   midmul = NSQ (mid = x)
//   x-pass: stride = NSQ, midmul = N   (mid = y)
// Global loads/stores are 128-B contiguous per 16 lanes.
// ---------------------------------------------------------------------------
__global__ __launch_bounds__(256) void k_fft_strided(float2* __restrict__ Z,
                                                     int stride, int midmul) {
    __shared__ float2 A[N * TP], B[N * TP];
    const int t   = threadIdx.x;
    const int zt  = blockIdx.x & 7;
    const int mid = (blockIdx.x >> 3) & (N - 1);
    const int bl  = blockIdx.x >> 10;
    const size_t base = (size_t)bl * VOL + (size_t)mid * midmul + (size_t)zt * TL;
#pragma unroll
    for (int i = 0; i < 8; ++i) {
        const int elem = i * 256 + t;
        const int zz = elem & (TL - 1);
        const int j  = elem >> 4;               // FFT coord
        A[j * TP + zz] = Z[base + (size_t)j * stride + zz];
    }
    float2* res = fft16(A, B, t);
#pragma unroll
    for (int i = 0; i < 8; ++i) {
        const int elem = i * 256 + t;
        const int zz = elem & (TL - 1);
        const int j  = elem >> 4;
        Z[base + (size_t)j * stride + zz] = res[j * TP + zz];
    }
}

// ---------------------------------------------------------------------------
// Pass 4: shell reduction. Recover F1/F2 from Z(k), Z(-k); accumulate
// cross / |F1|^2 / |F2|^2 into per-block LDS bins, then global atomics.
// ---------------------------------------------------------------------------
__global__ __launch_bounds__(256) void k_reduce(const float2* __restrict__ Z,
                                                const int* __restrict__ sidx,
                                                float* __restrict__ accum, int b0) {
    __shared__ float sh[NSHELL * 3];
    const int tid = threadIdx.x;
    for (int i = tid; i < NSHELL * 3; i += 256) sh[i] = 0.f;
    __syncthreads();
    const int bl    = blockIdx.x >> 8;
    const int chunk = blockIdx.x & 255;
    const size_t zb = (size_t)bl * VOL;
    const int k0 = chunk * 8192;
    for (int i = 0; i < 8192; i += 256) {
        const int k = k0 + i + tid;
        const int s = sidx[k];
        if (s < NSHELL) {
            const int x = k >> (2 * LOGN);
            const int y = (k >> LOGN) & (N - 1);
            const int z = k & (N - 1);
            const int mk = (((N - x) & (N - 1)) << (2 * LOGN)) |
                           (((N - y) & (N - 1)) << LOGN) |
                           ((N - z) & (N - 1));
            const float2 Av = Z[zb + k];
            const float2 Bv = Z[zb + mk];
            const float F1x = 0.5f * (Av.x + Bv.x);
            const float F1y = 0.5f * (Av.y - Bv.y);
            const float F2x = 0.5f * (Av.y + Bv.y);
            const float F2y = 0.5f * (Bv.x - Av.x);
            atomicAdd(&sh[s * 3 + 0], F1x * F2x + F1y * F2y);
            atomicAdd(&sh[s * 3 + 1], F1x * F1x + F1y * F1y);
            atomicAdd(&sh[s * 3 + 2], F2x * F2x + F2y * F2y);
        }
    }
    __syncthreads();
    float* acc = accum + (size_t)(b0 + bl) * (NSHELL * 3);
    for (int i = tid; i < NSHELL * 3; i += 256) atomicAdd(&acc[i], sh[i]);
}

// ---------------------------------------------------------------------------
// Pass 5: FSC + loss. 512 threads = 8 batches x 64 shells.
// ---------------------------------------------------------------------------
__global__ __launch_bounds__(512) void k_final(const float* __restrict__ accum,
                                               float* __restrict__ out) {
    __shared__ float red[8];
    const int tid = threadIdx.x;
    const float* a = accum + (size_t)tid * 3;
    const float fsc = a[0] / (sqrtf(a[1] * a[2]) + 1e-8f);
    float v = fsc * fsc;
#pragma unroll
    for (int off = 32; off > 0; off >>= 1) v += __shfl_down(v, off);
    if ((tid & 63) == 0) red[tid >> 6] = v;
    __syncthreads();
    if (tid == 0) {
        float ssum = 0.f;
#pragma unroll
        for (int i = 0; i < 8; ++i) ssum += red[i];
        out[0] = 1.0f - ssum / 512.0f;
    }
}

extern "C" void kernel_launch(void* const* d_in, const int* in_sizes, int n_in,
                              void* d_out, int out_size, void* d_ws, size_t ws_size,
                              hipStream_t stream) {
    const float* ref  = (const float*)d_in[0];
    const float* pred = (const float*)d_in[1];
    const int*   sidx = (const int*)d_in[2];
    float* out = (float*)d_out;

    char*   ws    = (char*)d_ws;
    float*  accum = (float*)ws;                    // 8*64*3 floats
    float2* Zbuf  = (float2*)(ws + 8192);

    const size_t zbytes = (size_t)VOL * sizeof(float2);
    int cap = 1;
    if (ws_size > 8192) {
        size_t c = (ws_size - 8192) / zbytes;
        cap = (c < 1) ? 1 : (c > BTOT ? BTOT : (int)c);
    }

    hipMemsetAsync(accum, 0, BTOT * NSHELL * 3 * sizeof(float), stream);

    for (int b0 = 0; b0 < BTOT; b0 += cap) {
        const int nb = (BTOT - b0 < cap) ? (BTOT - b0) : cap;
        const int nblk = nb * 1024;                // nb * 128 * 8 tiles
        k_fftz_pack<<<nblk, 256, 0, stream>>>(ref, pred, Zbuf, b0);
        k_fft_strided<<<nblk, 256, 0, stream>>>(Zbuf, N, NSQ);   // y-pass
        k_fft_strided<<<nblk, 256, 0, stream>>>(Zbuf, NSQ, N);   // x-pass
        k_reduce<<<nb * 256, 256, 0, stream>>>(Zbuf, sidx, accum, b0);
    }
    k_final<<<1, 512, 0, stream>>>(accum, out);
}

// Round 3
// 465.756 us; speedup vs baseline: 2.6534x; 1.0299x over previous
//
#include <hip/hip_runtime.h>
#include <math.h>

#define N      128
#define LOGN   7
#define NSQ    (N * N)          // 16384
#define VOL    (N * N * N)      // 2097152
#define NSHELL 64
#define BTOT   8
#define FPI    3.14159265358979323846f

#define TL     16               // lines per tile (FFT passes)
#define TP     (TL + 1)         // padded row stride in float2

// ---------------------------------------------------------------------------
// 16 simultaneous 128-point radix-2 Stockham FFTs over an LDS tile.
// ---------------------------------------------------------------------------
__device__ inline float2* fft16(float2* A, float2* B, int t) {
    const int bf  = t & 63;
    const int grp = (t >> 6) << 2;
    float2* src = A;
    float2* dst = B;
#pragma unroll
    for (int s = 0; s < LOGN; ++s) {
        const int Ns = 1 << s;
        const int m  = bf & (Ns - 1);
        const int d  = ((bf >> s) << (s + 1)) + m;
        float sw, cw;
        __sincosf(-FPI * (float)m / (float)Ns, &sw, &cw);
        __syncthreads();
#pragma unroll
        for (int l = 0; l < 4; ++l) {
            const int line = grp + l;
            const float2 v0 = src[bf * TP + line];
            const float2 v1 = src[(bf + 64) * TP + line];
            const float wx = v1.x * cw - v1.y * sw;
            const float wy = v1.x * sw + v1.y * cw;
            dst[d * TP + line]        = make_float2(v0.x + wx, v0.y + wy);
            dst[(d + Ns) * TP + line] = make_float2(v0.x - wx, v0.y - wy);
        }
        float2* tmp = src; src = dst; dst = tmp;
    }
    __syncthreads();
    return src;
}

// ---------------------------------------------------------------------------
// Pass 1: pack Z = ref + i*pred and FFT along z (contiguous axis).
// ---------------------------------------------------------------------------
__global__ __launch_bounds__(256) void k_fftz_pack(const float* __restrict__ ref,
                                                   const float* __restrict__ pred,
                                                   float2* __restrict__ Z, int b0) {
    __shared__ float2 A[N * TP], B[N * TP];
    const int t  = threadIdx.x;
    const int yt = blockIdx.x & 7;
    const int x  = (blockIdx.x >> 3) & (N - 1);
    const int bl = blockIdx.x >> 10;
    const size_t inbase = (size_t)(b0 + bl) * VOL + (size_t)x * NSQ + (size_t)yt * TL * N;
    const size_t zbase  = (size_t)bl * VOL + (size_t)x * NSQ + (size_t)yt * TL * N;
#pragma unroll
    for (int i = 0; i < 8; ++i) {
        const int elem = i * 256 + t;
        const int z = elem & (N - 1);
        const int j = elem >> LOGN;
        A[z * TP + j] = make_float2(ref[inbase + elem], pred[inbase + elem]);
    }
    float2* res = fft16(A, B, t);
#pragma unroll
    for (int i = 0; i < 8; ++i) {
        const int elem = i * 256 + t;
        const int z = elem & (N - 1);
        const int j = elem >> LOGN;
        Z[zbase + elem] = res[z * TP + j];
    }
}

// ---------------------------------------------------------------------------
// Passes 2 & 3: FFT along a strided axis.
// ---------------------------------------------------------------------------
__global__ __launch_bounds__(256) void k_fft_strided(float2* __restrict__ Z,
                                                     int stride, int midmul) {
    __shared__ float2 A[N * TP], B[N * TP];
    const int t   = threadIdx.x;
    const int zt  = blockIdx.x & 7;
    const int mid = (blockIdx.x >> 3) & (N - 1);
    const int bl  = blockIdx.x >> 10;
    const size_t base = (size_t)bl * VOL + (size_t)mid * midmul + (size_t)zt * TL;
#pragma unroll
    for (int i = 0; i < 8; ++i) {
        const int elem = i * 256 + t;
        const int zz = elem & (TL - 1);
        const int j  = elem >> 4;
        A[j * TP + zz] = Z[base + (size_t)j * stride + zz];
    }
    float2* res = fft16(A, B, t);
#pragma unroll
    for (int i = 0; i < 8; ++i) {
        const int elem = i * 256 + t;
        const int zz = elem & (TL - 1);
        const int j  = elem >> 4;
        Z[base + (size_t)j * stride + zz] = res[j * TP + zz];
    }
}

// ---------------------------------------------------------------------------
// Exact floor(sqrt(r2)) for integer r2 (r2 <= 3*64^2, exactly representable).
// ---------------------------------------------------------------------------
__device__ inline int isqrt_i(int r2) {
    int s = (int)sqrtf((float)r2);
    s -= (s * s > r2);
    s += ((s + 1) * (s + 1) <= r2);
    return s;
}

// ---------------------------------------------------------------------------
// Pass 4: shell reduction, serialization-free.
// Block = (batch, x, z-half): 256 threads; thread = (y = tid&127,
// zq = 2*half + (tid>>7)) owns a 32-long consecutive z run of line (x,y).
// Shell index is monotone along the run -> register run-length accumulation,
// flush to one of 4 padded LDS bin copies only on shell change. Loads of
// Z(k)/Z(-k) are gated on s < NSHELL (skips ~48% of k-space).
// ---------------------------------------------------------------------------
__global__ __launch_bounds__(256) void k_reduce(const float2* __restrict__ Z,
                                                float* __restrict__ accum, int b0) {
    __shared__ float sh[4 * 193];          // 4 copies of 64*3, padded to 193
    const int tid = threadIdx.x;
    for (int i = tid; i < 4 * 193; i += 256) sh[i] = 0.f;
    __syncthreads();

    const int bl = blockIdx.x >> 8;
    const int x  = (blockIdx.x >> 1) & (N - 1);
    const int h  = blockIdx.x & 1;
    const int y  = tid & (N - 1);
    const int zq = h * 2 + (tid >> 7);     // 0..3, 32 z each

    const int fx = x - ((x >= 64) ? N : 0);
    const int fy = y - ((y >= 64) ? N : 0);
    const int rho2 = fx * fx + fy * fy;
    const int mx = (N - x) & (N - 1);
    const int my = (N - y) & (N - 1);

    const size_t zb = (size_t)bl * VOL;
    const float2* Arow = Z + zb + (size_t)x * NSQ + (size_t)y * N;
    const float2* Brow = Z + zb + (size_t)mx * NSQ + (size_t)my * N;

    float* bins = sh + (tid & 3) * 193;

    float aC = 0.f, aP1 = 0.f, aP2 = 0.f;
    int cs = -1;
    const int z0 = zq * 32;
#pragma unroll 4
    for (int i = 0; i < 32; ++i) {
        const int z  = z0 + i;
        const int fz = z - ((z >= 64) ? N : 0);
        const int s  = isqrt_i(rho2 + fz * fz);
        if (s != cs) {
            if (cs >= 0 && cs < NSHELL) {
                atomicAdd(&bins[cs * 3 + 0], aC);
                atomicAdd(&bins[cs * 3 + 1], aP1);
                atomicAdd(&bins[cs * 3 + 2], aP2);
            }
            cs = s; aC = 0.f; aP1 = 0.f; aP2 = 0.f;
        }
        if (s < NSHELL) {
            const float2 Av = Arow[z];
            const float2 Bv = Brow[(N - z) & (N - 1)];
            const float F1x = 0.5f * (Av.x + Bv.x);
            const float F1y = 0.5f * (Av.y - Bv.y);
            const float F2x = 0.5f * (Av.y + Bv.y);
            const float F2y = 0.5f * (Bv.x - Av.x);
            aC  += F1x * F2x + F1y * F2y;
            aP1 += F1x * F1x + F1y * F1y;
            aP2 += F2x * F2x + F2y * F2y;
        }
    }
    if (cs >= 0 && cs < NSHELL) {
        atomicAdd(&bins[cs * 3 + 0], aC);
        atomicAdd(&bins[cs * 3 + 1], aP1);
        atomicAdd(&bins[cs * 3 + 2], aP2);
    }
    __syncthreads();

    float* acc = accum + (size_t)(b0 + bl) * (NSHELL * 3);
    for (int i = tid; i < NSHELL * 3; i += 256) {
        const float v = sh[i] + sh[193 + i] + sh[2 * 193 + i] + sh[3 * 193 + i];
        atomicAdd(&acc[i], v);
    }
}

// ---------------------------------------------------------------------------
// Pass 5: FSC + loss. 512 threads = 8 batches x 64 shells.
// ---------------------------------------------------------------------------
__global__ __launch_bounds__(512) void k_final(const float* __restrict__ accum,
                                               float* __restrict__ out) {
    __shared__ float red[8];
    const int tid = threadIdx.x;
    const float* a = accum + (size_t)tid * 3;
    const float fsc = a[0] / (sqrtf(a[1] * a[2]) + 1e-8f);
    float v = fsc * fsc;
#pragma unroll
    for (int off = 32; off > 0; off >>= 1) v += __shfl_down(v, off);
    if ((tid & 63) == 0) red[tid >> 6] = v;
    __syncthreads();
    if (tid == 0) {
        float ssum = 0.f;
#pragma unroll
        for (int i = 0; i < 8; ++i) ssum += red[i];
        out[0] = 1.0f - ssum / 512.0f;
    }
}

extern "C" void kernel_launch(void* const* d_in, const int* in_sizes, int n_in,
                              void* d_out, int out_size, void* d_ws, size_t ws_size,
                              hipStream_t stream) {
    const float* ref  = (const float*)d_in[0];
    const float* pred = (const float*)d_in[1];
    float* out = (float*)d_out;

    char*   ws    = (char*)d_ws;
    float*  accum = (float*)ws;
    float2* Zbuf  = (float2*)(ws + 8192);

    const size_t zbytes = (size_t)VOL * sizeof(float2);
    int cap = 1;
    if (ws_size > 8192) {
        size_t c = (ws_size - 8192) / zbytes;
        cap = (c < 1) ? 1 : (c > BTOT ? BTOT : (int)c);
    }

    hipMemsetAsync(accum, 0, BTOT * NSHELL * 3 * sizeof(float), stream);

    for (int b0 = 0; b0 < BTOT; b0 += cap) {
        const int nb = (BTOT - b0 < cap) ? (BTOT - b0) : cap;
        const int nblk = nb * 1024;
        k_fftz_pack<<<nblk, 256, 0, stream>>>(ref, pred, Zbuf, b0);
        k_fft_strided<<<nblk, 256, 0, stream>>>(Zbuf, N, NSQ);   // y-pass
        k_fft_strided<<<nblk, 256, 0, stream>>>(Zbuf, NSQ, N);   // x-pass
        k_reduce<<<nb * 256, 256, 0, stream>>>(Zbuf, accum, b0);
    }
    k_final<<<1, 512, 0, stream>>>(accum, out);
}

// Round 4
// 370.789 us; speedup vs baseline: 3.3330x; 1.2561x over previous
//
#include <hip/hip_runtime.h>
#include <math.h>

#define N      128
#define LOGN   7
#define NSQ    (N * N)          // 16384
#define VOL    (N * N * N)      // 2097152
#define NSHELL 64
#define BTOT   8
#define FPI    3.14159265358979323846f

#define TL     16               // lines per tile (FFT passes)
#define TP     (TL + 1)         // padded row stride in float2

// ---------------------------------------------------------------------------
// 16 simultaneous 128-point radix-2 Stockham FFTs over an LDS tile.
// ---------------------------------------------------------------------------
__device__ inline float2* fft16(float2* A, float2* B, int t) {
    const int bf  = t & 63;
    const int grp = (t >> 6) << 2;
    float2* src = A;
    float2* dst = B;
#pragma unroll
    for (int s = 0; s < LOGN; ++s) {
        const int Ns = 1 << s;
        const int m  = bf & (Ns - 1);
        const int d  = ((bf >> s) << (s + 1)) + m;
        float sw, cw;
        __sincosf(-FPI * (float)m / (float)Ns, &sw, &cw);
        __syncthreads();
#pragma unroll
        for (int l = 0; l < 4; ++l) {
            const int line = grp + l;
            const float2 v0 = src[bf * TP + line];
            const float2 v1 = src[(bf + 64) * TP + line];
            const float wx = v1.x * cw - v1.y * sw;
            const float wy = v1.x * sw + v1.y * cw;
            dst[d * TP + line]        = make_float2(v0.x + wx, v0.y + wy);
            dst[(d + Ns) * TP + line] = make_float2(v0.x - wx, v0.y - wy);
        }
        float2* tmp = src; src = dst; dst = tmp;
    }
    __syncthreads();
    return src;
}

// ---------------------------------------------------------------------------
// Pass 1: pack Z = ref + i*pred and FFT along z (contiguous axis).
// ---------------------------------------------------------------------------
__global__ __launch_bounds__(256) void k_fftz_pack(const float* __restrict__ ref,
                                                   const float* __restrict__ pred,
                                                   float2* __restrict__ Z, int b0) {
    __shared__ float2 A[N * TP], B[N * TP];
    const int t  = threadIdx.x;
    const int yt = blockIdx.x & 7;
    const int x  = (blockIdx.x >> 3) & (N - 1);
    const int bl = blockIdx.x >> 10;
    const size_t inbase = (size_t)(b0 + bl) * VOL + (size_t)x * NSQ + (size_t)yt * TL * N;
    const size_t zbase  = (size_t)bl * VOL + (size_t)x * NSQ + (size_t)yt * TL * N;
#pragma unroll
    for (int i = 0; i < 8; ++i) {
        const int elem = i * 256 + t;
        const int z = elem & (N - 1);
        const int j = elem >> LOGN;
        A[z * TP + j] = make_float2(ref[inbase + elem], pred[inbase + elem]);
    }
    float2* res = fft16(A, B, t);
#pragma unroll
    for (int i = 0; i < 8; ++i) {
        const int elem = i * 256 + t;
        const int z = elem & (N - 1);
        const int j = elem >> LOGN;
        Z[zbase + elem] = res[z * TP + j];
    }
}

// ---------------------------------------------------------------------------
// Passes 2 & 3: FFT along a strided axis.
// ---------------------------------------------------------------------------
__global__ __launch_bounds__(256) void k_fft_strided(float2* __restrict__ Z,
                                                     int stride, int midmul) {
    __shared__ float2 A[N * TP], B[N * TP];
    const int t   = threadIdx.x;
    const int zt  = blockIdx.x & 7;
    const int mid = (blockIdx.x >> 3) & (N - 1);
    const int bl  = blockIdx.x >> 10;
    const size_t base = (size_t)bl * VOL + (size_t)mid * midmul + (size_t)zt * TL;
#pragma unroll
    for (int i = 0; i < 8; ++i) {
        const int elem = i * 256 + t;
        const int zz = elem & (TL - 1);
        const int j  = elem >> 4;
        A[j * TP + zz] = Z[base + (size_t)j * stride + zz];
    }
    float2* res = fft16(A, B, t);
#pragma unroll
    for (int i = 0; i < 8; ++i) {
        const int elem = i * 256 + t;
        const int zz = elem & (TL - 1);
        const int j  = elem >> 4;
        Z[base + (size_t)j * stride + zz] = res[j * TP + zz];
    }
}

// ---------------------------------------------------------------------------
// Exact floor(sqrt(r2)) for integer r2 (r2 <= 3*64^2, exactly representable).
// ---------------------------------------------------------------------------
__device__ inline int isqrt_i(int r2) {
    int s = (int)sqrtf((float)r2);
    s -= (s * s > r2);
    s += ((s + 1) * (s + 1) <= r2);
    return s;
}

// ---------------------------------------------------------------------------
// Pass 4: shell reduction, coalesced along z.
// Block = (batch, x, 16-y tile). Thread (z = tid&127, ysub = tid>>7) walks
// 8 y's of the line (x, y, .): wave loads are 64 consecutive float2 of one
// line (512 B contiguous); partner line (mx, my) is read reversed-contiguous
// within its 1 KB row. Shell index exact-isqrt per element; register
// run-length accumulation along y, flush on shell change into one of 4
// padded LDS bin copies. Block early-exits when the whole tile lies outside
// the Nyquist sphere; per-lane loads are gated on s < NSHELL.
// ---------------------------------------------------------------------------
__global__ __launch_bounds__(256) void k_reduce(const float2* __restrict__ Z,
                                                float* __restrict__ accum, int b0) {
    const int tid = threadIdx.x;
    const int bl  = blockIdx.x >> 10;          // 1024 blocks per batch
    const int x   = (blockIdx.x >> 3) & (N - 1);
    const int y0  = (blockIdx.x & 7) * 16;
    const int z   = tid & (N - 1);
    const int ys  = (tid >> 7) * 8;            // 0 or 8

    const int fx = x - ((x >= 64) ? N : 0);
    const int fz = z - ((z >= 64) ? N : 0);

    // whole-tile early exit: min |fy| over y in [y0, y0+16)
    const int minfy = (y0 < 64) ? y0 : (113 - y0);
    if (fx * fx + minfy * minfy >= 4096) return;   // block-uniform

    __shared__ float sh[4 * 193];
    for (int i = tid; i < 4 * 193; i += 256) sh[i] = 0.f;
    __syncthreads();

    const int mx = (N - x) & (N - 1);
    const int mz = (N - z) & (N - 1);
    const size_t zb = (size_t)bl * VOL;
    const float2* Ap = Z + zb + (size_t)x  * NSQ + z;    // + y*N per iter
    const float2* Bp = Z + zb + (size_t)mx * NSQ + mz;   // + my*N per iter

    float* bins = sh + (tid & 3) * 193;
    const int fzz = fz * fz;
    const int fxx = fx * fx;

    float aC = 0.f, aP1 = 0.f, aP2 = 0.f;
    int cs = -1;
#pragma unroll
    for (int j = 0; j < 8; ++j) {
        const int y  = y0 + ys + j;
        const int fy = y - ((y >= 64) ? N : 0);
        const int s  = isqrt_i(fxx + fy * fy + fzz);
        if (s != cs) {
            if (cs >= 0 && cs < NSHELL) {
                atomicAdd(&bins[cs * 3 + 0], aC);
                atomicAdd(&bins[cs * 3 + 1], aP1);
                atomicAdd(&bins[cs * 3 + 2], aP2);
            }
            cs = s; aC = 0.f; aP1 = 0.f; aP2 = 0.f;
        }
        if (s < NSHELL) {
            const int my = (N - y) & (N - 1);
            const float2 Av = Ap[(size_t)y  * N];
            const float2 Bv = Bp[(size_t)my * N];
            const float F1x = 0.5f * (Av.x + Bv.x);
            const float F1y = 0.5f * (Av.y - Bv.y);
            const float F2x = 0.5f * (Av.y + Bv.y);
            const float F2y = 0.5f * (Bv.x - Av.x);
            aC  += F1x * F2x + F1y * F2y;
            aP1 += F1x * F1x + F1y * F1y;
            aP2 += F2x * F2x + F2y * F2y;
        }
    }
    if (cs >= 0 && cs < NSHELL) {
        atomicAdd(&bins[cs * 3 + 0], aC);
        atomicAdd(&bins[cs * 3 + 1], aP1);
        atomicAdd(&bins[cs * 3 + 2], aP2);
    }
    __syncthreads();

    float* acc = accum + (size_t)(b0 + bl) * (NSHELL * 3);
    for (int i = tid; i < NSHELL * 3; i += 256) {
        const float v = sh[i] + sh[193 + i] + sh[2 * 193 + i] + sh[3 * 193 + i];
        atomicAdd(&acc[i], v);
    }
}

// ---------------------------------------------------------------------------
// Pass 5: FSC + loss. 512 threads = 8 batches x 64 shells.
// ---------------------------------------------------------------------------
__global__ __launch_bounds__(512) void k_final(const float* __restrict__ accum,
                                               float* __restrict__ out) {
    __shared__ float red[8];
    const int tid = threadIdx.x;
    const float* a = accum + (size_t)tid * 3;
    const float fsc = a[0] / (sqrtf(a[1] * a[2]) + 1e-8f);
    float v = fsc * fsc;
#pragma unroll
    for (int off = 32; off > 0; off >>= 1) v += __shfl_down(v, off);
    if ((tid & 63) == 0) red[tid >> 6] = v;
    __syncthreads();
    if (tid == 0) {
        float ssum = 0.f;
#pragma unroll
        for (int i = 0; i < 8; ++i) ssum += red[i];
        out[0] = 1.0f - ssum / 512.0f;
    }
}

extern "C" void kernel_launch(void* const* d_in, const int* in_sizes, int n_in,
                              void* d_out, int out_size, void* d_ws, size_t ws_size,
                              hipStream_t stream) {
    const float* ref  = (const float*)d_in[0];
    const float* pred = (const float*)d_in[1];
    float* out = (float*)d_out;

    char*   ws    = (char*)d_ws;
    float*  accum = (float*)ws;
    float2* Zbuf  = (float2*)(ws + 8192);

    const size_t zbytes = (size_t)VOL * sizeof(float2);
    int cap = 1;
    if (ws_size > 8192) {
        size_t c = (ws_size - 8192) / zbytes;
        cap = (c < 1) ? 1 : (c > BTOT ? BTOT : (int)c);
    }

    hipMemsetAsync(accum, 0, BTOT * NSHELL * 3 * sizeof(float), stream);

    for (int b0 = 0; b0 < BTOT; b0 += cap) {
        const int nb = (BTOT - b0 < cap) ? (BTOT - b0) : cap;
        const int nblk = nb * 1024;
        k_fftz_pack<<<nblk, 256, 0, stream>>>(ref, pred, Zbuf, b0);
        k_fft_strided<<<nblk, 256, 0, stream>>>(Zbuf, N, NSQ);   // y-pass
        k_fft_strided<<<nblk, 256, 0, stream>>>(Zbuf, NSQ, N);   // x-pass
        k_reduce<<<nblk, 256, 0, stream>>>(Zbuf, accum, b0);
    }
    k_final<<<1, 512, 0, stream>>>(accum, out);
}

// Round 5
// 313.876 us; speedup vs baseline: 3.9373x; 1.1813x over previous
//
#include <hip/hip_runtime.h>
#include <math.h>

#define N      128
#define LOGN   7
#define NSQ    (N * N)          // 16384
#define VOL    (N * N * N)      // 2097152
#define NSHELL 64
#define BTOT   8
#define FPI    3.14159265358979323846f

#define TL     16               // lines per tile (FFT passes)
#define TP     (TL + 1)         // padded row stride in float2

// ---------------------------------------------------------------------------
// 16 simultaneous 128-point Stockham FFTs over an LDS tile, radix-4 fused:
// stages (0,1),(2,3),(4,5) each do two radix-2 levels in registers (one LDS
// round each), then one radix-2 stage s=6. 4 LDS rounds instead of 7.
// Derivation: compose radix-2 Stockham maps. For the fused stage at Ns=2^s,
// thread j = c*Ns + m (j in [0,32)):
//   a = src[j], cc = src[j+32], b = src[j+64], d = src[j+96]
//   w = exp(-i pi m/Ns) = w2m^2,  w2m = exp(-i pi m/(2Ns))
//   Ap = a + w*b; Am = a - w*b; Bp = cc + w*d; Bm = cc - w*d
//   out[c*4Ns+m]      = Ap + w2m*Bp
//   out[c*4Ns+m+Ns]   = Am - i*w2m*Bm
//   out[c*4Ns+m+2Ns]  = Ap - w2m*Bp
//   out[c*4Ns+m+3Ns]  = Am + i*w2m*Bm
// ---------------------------------------------------------------------------
__device__ inline float2* fft16(float2* A, float2* B, int t) {
    const int j5 = t & 31;           // butterfly-4 index
    const int lg = (t >> 5) << 1;    // 2 lines per thread
    float2* src = A;
    float2* dst = B;
#pragma unroll
    for (int s = 0; s < 6; s += 2) {
        const int Ns = 1 << s;
        const int m  = j5 & (Ns - 1);
        const int cc = j5 >> s;
        const int e0 = (cc << (s + 2)) + m;      // c*4Ns + m
        float s2, c2;
        __sincosf(-FPI * (float)m / (float)(2 * Ns), &s2, &c2);
        const float cw = c2 * c2 - s2 * s2;      // w = w2m^2
        const float sw = 2.f * c2 * s2;
        __syncthreads();
#pragma unroll
        for (int l = 0; l < 2; ++l) {
            const int line = lg + l;
            const float2 a  = src[ j5       * TP + line];
            const float2 cv = src[(j5 + 32) * TP + line];
            const float2 b  = src[(j5 + 64) * TP + line];
            const float2 d  = src[(j5 + 96) * TP + line];
            const float wbx = b.x * cw - b.y * sw, wby = b.x * sw + b.y * cw;
            const float wdx = d.x * cw - d.y * sw, wdy = d.x * sw + d.y * cw;
            const float Apx = a.x + wbx, Apy = a.y + wby;
            const float Amx = a.x - wbx, Amy = a.y - wby;
            const float Bpx = cv.x + wdx, Bpy = cv.y + wdy;
            const float Bmx = cv.x - wdx, Bmy = cv.y - wdy;
            const float t0x = Bpx * c2 - Bpy * s2, t0y = Bpx * s2 + Bpy * c2;
            const float t1x = Bmx * c2 - Bmy * s2, t1y = Bmx * s2 + Bmy * c2;
            dst[(e0)          * TP + line] = make_float2(Apx + t0x, Apy + t0y);
            dst[(e0 + Ns)     * TP + line] = make_float2(Amx + t1y, Amy - t1x);
            dst[(e0 + 2 * Ns) * TP + line] = make_float2(Apx - t0x, Apy - t0y);
            dst[(e0 + 3 * Ns) * TP + line] = make_float2(Amx - t1y, Amy + t1x);
        }
        float2* tmp = src; src = dst; dst = tmp;
    }
    // final radix-2 stage, s=6 (Ns=64): d = m, pairs (m, m+64)
    {
        const int m   = t & 63;
        const int grp = (t >> 6) << 2;
        float sw, cw;
        __sincosf(-FPI * (float)m / 64.f, &sw, &cw);
        __syncthreads();
#pragma unroll
        for (int l = 0; l < 4; ++l) {
            const int line = grp + l;
            const float2 v0 = src[m * TP + line];
            const float2 v1 = src[(m + 64) * TP + line];
            const float wx = v1.x * cw - v1.y * sw;
            const float wy = v1.x * sw + v1.y * cw;
            dst[m * TP + line]        = make_float2(v0.x + wx, v0.y + wy);
            dst[(m + 64) * TP + line] = make_float2(v0.x - wx, v0.y - wy);
        }
    }
    __syncthreads();
    return dst;
}

// ---------------------------------------------------------------------------
// Pass 1: pack Z = ref + i*pred and FFT along z (contiguous axis).
// ---------------------------------------------------------------------------
__global__ __launch_bounds__(256) void k_fftz_pack(const float* __restrict__ ref,
                                                   const float* __restrict__ pred,
                                                   float2* __restrict__ Z, int b0) {
    __shared__ float2 A[N * TP], B[N * TP];
    const int t  = threadIdx.x;
    const int yt = blockIdx.x & 7;
    const int x  = (blockIdx.x >> 3) & (N - 1);
    const int bl = blockIdx.x >> 10;
    const size_t inbase = (size_t)(b0 + bl) * VOL + (size_t)x * NSQ + (size_t)yt * TL * N;
    const size_t zbase  = (size_t)bl * VOL + (size_t)x * NSQ + (size_t)yt * TL * N;
#pragma unroll
    for (int i = 0; i < 8; ++i) {
        const int elem = i * 256 + t;
        const int z = elem & (N - 1);
        const int j = elem >> LOGN;
        A[z * TP + j] = make_float2(ref[inbase + elem], pred[inbase + elem]);
    }
    float2* res = fft16(A, B, t);
#pragma unroll
    for (int i = 0; i < 8; ++i) {
        const int elem = i * 256 + t;
        const int z = elem & (N - 1);
        const int j = elem >> LOGN;
        Z[zbase + elem] = res[z * TP + j];
    }
}

// ---------------------------------------------------------------------------
// Passes 2 & 3: FFT along a strided axis.
// ---------------------------------------------------------------------------
__global__ __launch_bounds__(256) void k_fft_strided(float2* __restrict__ Z,
                                                     int stride, int midmul) {
    __shared__ float2 A[N * TP], B[N * TP];
    const int t   = threadIdx.x;
    const int zt  = blockIdx.x & 7;
    const int mid = (blockIdx.x >> 3) & (N - 1);
    const int bl  = blockIdx.x >> 10;
    const size_t base = (size_t)bl * VOL + (size_t)mid * midmul + (size_t)zt * TL;
#pragma unroll
    for (int i = 0; i < 8; ++i) {
        const int elem = i * 256 + t;
        const int zz = elem & (TL - 1);
        const int j  = elem >> 4;
        A[j * TP + zz] = Z[base + (size_t)j * stride + zz];
    }
    float2* res = fft16(A, B, t);
#pragma unroll
    for (int i = 0; i < 8; ++i) {
        const int elem = i * 256 + t;
        const int zz = elem & (TL - 1);
        const int j  = elem >> 4;
        Z[base + (size_t)j * stride + zz] = res[j * TP + zz];
    }
}

// ---------------------------------------------------------------------------
// Exact floor(sqrt(r2)) for integer r2.
// ---------------------------------------------------------------------------
__device__ inline int isqrt_i(int r2) {
    int s = (int)sqrtf((float)r2);
    s -= (s * s > r2);
    s += ((s + 1) * (s + 1) <= r2);
    return s;
}

// ---------------------------------------------------------------------------
// Pass 4: Hermitian half-space shell reduction.
// contribution(k) == contribution(-k) (real inputs) and shell(-k)==shell(k),
// so enumerate y in [0,64) only: weight 2 for y in [1,63], weight 1 for the
// self-mapped y=0 plane (its partners also have y=0 and are enumerated).
// The y=64 plane has r >= 64 -> s >= NSHELL -> contributes nothing; dropped.
// Block = (batch, x, 16-y tile of 4 tiles). Thread (z = tid&127, ys) walks
// 8 y's; wave loads are contiguous along z. Register run-length accumulation
// along y, flush on shell change into 4 padded LDS bin copies.
// ---------------------------------------------------------------------------
__global__ __launch_bounds__(256) void k_reduce(const float2* __restrict__ Z,
                                                float* __restrict__ accum, int b0) {
    const int tid = threadIdx.x;
    const int bl  = blockIdx.x >> 9;           // 512 blocks per batch
    const int x   = (blockIdx.x >> 2) & (N - 1);
    const int y0  = (blockIdx.x & 3) * 16;     // 0,16,32,48
    const int z   = tid & (N - 1);
    const int ys  = (tid >> 7) * 8;            // 0 or 8

    const int fx = x - ((x >= 64) ? N : 0);
    const int fz = z - ((z >= 64) ? N : 0);

    // whole-tile early exit (block-uniform): min fy over tile = y0 (y < 64)
    if (fx * fx + y0 * y0 >= 4096) return;

    __shared__ float sh[4 * 193];
    for (int i = tid; i < 4 * 193; i += 256) sh[i] = 0.f;
    __syncthreads();

    const int mx = (N - x) & (N - 1);
    const int mz = (N - z) & (N - 1);
    const size_t zb = (size_t)bl * VOL;
    const float2* Ap = Z + zb + (size_t)x  * NSQ + z;
    const float2* Bp = Z + zb + (size_t)mx * NSQ + mz;

    float* bins = sh + (tid & 3) * 193;
    const int fxx = fx * fx;
    const int fzz = fz * fz;

    float aC = 0.f, aP1 = 0.f, aP2 = 0.f;
    int cs = -1;
#pragma unroll
    for (int j = 0; j < 8; ++j) {
        const int y  = y0 + ys + j;            // in [0,64)
        const int s  = isqrt_i(fxx + y * y + fzz);   // fy = y here
        if (s != cs) {
            if (cs >= 0 && cs < NSHELL) {
                atomicAdd(&bins[cs * 3 + 0], aC);
                atomicAdd(&bins[cs * 3 + 1], aP1);
                atomicAdd(&bins[cs * 3 + 2], aP2);
            }
            cs = s; aC = 0.f; aP1 = 0.f; aP2 = 0.f;
        }
        if (s < NSHELL) {
            const float w = (y == 0) ? 1.f : 2.f;
            const int my = (N - y) & (N - 1);
            const float2 Av = Ap[(size_t)y  * N];
            const float2 Bv = Bp[(size_t)my * N];
            const float F1x = 0.5f * (Av.x + Bv.x);
            const float F1y = 0.5f * (Av.y - Bv.y);
            const float F2x = 0.5f * (Av.y + Bv.y);
            const float F2y = 0.5f * (Bv.x - Av.x);
            aC  += w * (F1x * F2x + F1y * F2y);
            aP1 += w * (F1x * F1x + F1y * F1y);
            aP2 += w * (F2x * F2x + F2y * F2y);
        }
    }
    if (cs >= 0 && cs < NSHELL) {
        atomicAdd(&bins[cs * 3 + 0], aC);
        atomicAdd(&bins[cs * 3 + 1], aP1);
        atomicAdd(&bins[cs * 3 + 2], aP2);
    }
    __syncthreads();

    float* acc = accum + (size_t)(b0 + bl) * (NSHELL * 3);
    for (int i = tid; i < NSHELL * 3; i += 256) {
        const float v = sh[i] + sh[193 + i] + sh[2 * 193 + i] + sh[3 * 193 + i];
        atomicAdd(&acc[i], v);
    }
}

// ---------------------------------------------------------------------------
// Pass 5: FSC + loss. 512 threads = 8 batches x 64 shells.
// ---------------------------------------------------------------------------
__global__ __launch_bounds__(512) void k_final(const float* __restrict__ accum,
                                               float* __restrict__ out) {
    __shared__ float red[8];
    const int tid = threadIdx.x;
    const float* a = accum + (size_t)tid * 3;
    const float fsc = a[0] / (sqrtf(a[1] * a[2]) + 1e-8f);
    float v = fsc * fsc;
#pragma unroll
    for (int off = 32; off > 0; off >>= 1) v += __shfl_down(v, off);
    if ((tid & 63) == 0) red[tid >> 6] = v;
    __syncthreads();
    if (tid == 0) {
        float ssum = 0.f;
#pragma unroll
        for (int i = 0; i < 8; ++i) ssum += red[i];
        out[0] = 1.0f - ssum / 512.0f;
    }
}

extern "C" void kernel_launch(void* const* d_in, const int* in_sizes, int n_in,
                              void* d_out, int out_size, void* d_ws, size_t ws_size,
                              hipStream_t stream) {
    const float* ref  = (const float*)d_in[0];
    const float* pred = (const float*)d_in[1];
    float* out = (float*)d_out;

    char*   ws    = (char*)d_ws;
    float*  accum = (float*)ws;
    float2* Zbuf  = (float2*)(ws + 8192);

    const size_t zbytes = (size_t)VOL * sizeof(float2);
    int cap = 1;
    if (ws_size > 8192) {
        size_t c = (ws_size - 8192) / zbytes;
        cap = (c < 1) ? 1 : (c > BTOT ? BTOT : (int)c);
    }

    hipMemsetAsync(accum, 0, BTOT * NSHELL * 3 * sizeof(float), stream);

    for (int b0 = 0; b0 < BTOT; b0 += cap) {
        const int nb = (BTOT - b0 < cap) ? (BTOT - b0) : cap;
        const int nblk = nb * 1024;
        k_fftz_pack<<<nblk, 256, 0, stream>>>(ref, pred, Zbuf, b0);
        k_fft_strided<<<nblk, 256, 0, stream>>>(Zbuf, N, NSQ);   // y-pass
        k_fft_strided<<<nblk, 256, 0, stream>>>(Zbuf, NSQ, N);   // x-pass
        k_reduce<<<nb * 512, 256, 0, stream>>>(Zbuf, accum, b0);
    }
    k_final<<<1, 512, 0, stream>>>(accum, out);
}